// Round 18
// baseline (2331.640 us; speedup 1.0000x reference)
//
#include <hip/hip_runtime.h>
#include <math.h>

#define N_NODES  100000
#define N_EDGES  3200000
#define K_IN     1433
#define NH       16
#define NO       7

// ---- gemm1 (R18): 96-row tiles, 64k granules (256B/row), in-kernel W restage
#define TR3      96                           // rows per wave-tile
#define NT3      1042                         // ceil(100000/96); 521 blocks x 2
#define SX3      68                           // X LDS row stride (floats)
#define NSPL     8                            // W slices of 192 k (8*192=1536)
#define SLOT     96

#define NBKT     256
#define BKN      391
#define SBLK     512
#define EPB      ((N_EDGES + SBLK - 1) / SBLK)

typedef float f4  __attribute__((ext_vector_type(4)));
typedef float f4u __attribute__((ext_vector_type(4), aligned(4)));

// ---------------- B1: both bucket histograms in one pass ----------------
__global__ __launch_bounds__(256)
void k_pcount2(const int* __restrict__ src, const int* __restrict__ dst,
               int* __restrict__ partial_s, int* __restrict__ partial_d) {
    __shared__ int lhd[NBKT], lhs[NBKT];
    lhd[threadIdx.x] = 0; lhs[threadIdx.x] = 0;
    __syncthreads();
    const int e0 = blockIdx.x * EPB;
    const int e1 = min(e0 + EPB, N_EDGES);
    for (int i = e0 + threadIdx.x; i < e1; i += 256) {
        atomicAdd(&lhd[dst[i] / BKN], 1);
        atomicAdd(&lhs[src[i] / BKN], 1);
    }
    __syncthreads();
    partial_d[blockIdx.x * NBKT + threadIdx.x] = lhd[threadIdx.x];
    partial_s[blockIdx.x * NBKT + threadIdx.x] = lhs[threadIdx.x];
}

// ---------------- B2: per-bucket scan of partials (both keys, 512 blocks) --
__global__ __launch_bounds__(256)
void k_colscan2(const int* __restrict__ pd, int* __restrict__ pbd,
                int* __restrict__ btd, const int* __restrict__ ps,
                int* __restrict__ pbs, int* __restrict__ bts) {
    __shared__ int s[256];
    const int blk = blockIdx.x, t = threadIdx.x;
    const int* partial = (blk < NBKT) ? pd : ps;
    int* pbase = (blk < NBKT) ? pbd : pbs;
    int* btot  = (blk < NBKT) ? btd : bts;
    const int b = (blk < NBKT) ? blk : blk - NBKT;
    const int v0 = partial[(2 * t)     * NBKT + b];
    const int v1 = partial[(2 * t + 1) * NBKT + b];
    const int pair = v0 + v1;
    s[t] = pair;
    __syncthreads();
    for (int o = 1; o < 256; o <<= 1) {
        int u = (t >= o) ? s[t - o] : 0;
        __syncthreads();
        s[t] += u;
        __syncthreads();
    }
    const int excl = s[t] - pair;
    pbase[(2 * t)     * NBKT + b] = excl;
    pbase[(2 * t + 1) * NBKT + b] = excl + v0;
    if (t == 255) btot[b] = s[255];
}

// ---------------- B3: exclusive scan of bucket totals (both keys) ----------
__global__ __launch_bounds__(256)
void k_basescan(const int* __restrict__ btd, int* __restrict__ bbd,
                const int* __restrict__ bts, int* __restrict__ bbs) {
    __shared__ int s[256];
    const int t = threadIdx.x;
    int v = btd[t];
    s[t] = v;
    __syncthreads();
    for (int o = 1; o < 256; o <<= 1) {
        int u = (t >= o) ? s[t - o] : 0;
        __syncthreads();
        s[t] += u;
        __syncthreads();
    }
    bbd[t] = s[t] - v;
    __syncthreads();
    v = bts[t];
    s[t] = v;
    __syncthreads();
    for (int o = 1; o < 256; o <<= 1) {
        int u = (t >= o) ? s[t - o] : 0;
        __syncthreads();
        s[t] += u;
        __syncthreads();
    }
    bbs[t] = s[t] - v;
}

// ---------------- B4: both scatters in one pass ----------------------------
__global__ __launch_bounds__(256)
void k_pscatter_both(const int* __restrict__ src, const int* __restrict__ dst,
                     const int* __restrict__ pbase_d, const int* __restrict__ bbase_d,
                     int2* __restrict__ ebuf,
                     const int* __restrict__ pbase_s, const int* __restrict__ bbase_s,
                     int* __restrict__ sbuf) {
    __shared__ int lhd[NBKT], lbd[NBKT], lhs[NBKT], lbs[NBKT];
    const int t = threadIdx.x;
    lhd[t] = 0; lhs[t] = 0;
    lbd[t] = bbase_d[t] + pbase_d[blockIdx.x * NBKT + t];
    lbs[t] = bbase_s[t] + pbase_s[blockIdx.x * NBKT + t];
    __syncthreads();
    const int e0 = blockIdx.x * EPB;
    const int e1 = min(e0 + EPB, N_EDGES);
    for (int i = e0 + t; i < e1; i += 256) {
        int sv = src[i], dv = dst[i];
        int bd = dv / BKN;
        int p  = lbd[bd] + atomicAdd(&lhd[bd], 1);
        ebuf[p] = make_int2(sv, dv);
        int bs = sv / BKN;
        int q  = lbs[bs] + atomicAdd(&lhs[bs], 1);
        sbuf[q] = sv;
    }
}

// ---------------- B5: adj build + src histogram, one kernel ----------------
__global__ __launch_bounds__(512)
void k_adj_hist(const int2* __restrict__ ebuf, const int* __restrict__ bbase_d,
                const int* __restrict__ btot_d, int* __restrict__ adj,
                int* __restrict__ cnt,
                const int* __restrict__ sbuf, const int* __restrict__ bbase_s,
                const int* __restrict__ btot_s, int* __restrict__ deg) {
    __shared__ int cur[BKN];
    const int b = blockIdx.x;
    const int nb = b * BKN;
    for (int i = threadIdx.x; i < BKN; i += 512) cur[i] = 0;
    __syncthreads();
    // part A: slotted adjacency by dst + exact in-degree
    {
        const int s0 = bbase_d[b], s1 = s0 + btot_d[b];
        for (int i = s0 + threadIdx.x; i < s1; i += 512) {
            int2 e = ebuf[i];
            int p = atomicAdd(&cur[e.y - nb], 1);
            if (p < SLOT) adj[e.y * SLOT + p] = e.x;
        }
    }
    __syncthreads();
    for (int i = threadIdx.x; i < BKN; i += 512) {
        int n = nb + i;
        if (n < N_NODES) cnt[n] = cur[i];
    }
    __syncthreads();
    for (int i = threadIdx.x; i < BKN; i += 512) cur[i] = 0;
    __syncthreads();
    // part B: out-degree histogram from src-sorted buffer
    {
        const int s0 = bbase_s[b], s1 = s0 + btot_s[b];
        for (int i = s0 + threadIdx.x; i < s1; i += 512)
            atomicAdd(&cur[sbuf[i] - nb], 1);
    }
    __syncthreads();
    for (int i = threadIdx.x; i < BKN; i += 512) {
        int n = nb + i;
        if (n < N_NODES) deg[n] = cur[i];
    }
}

// ---------------- K2: h = norm_src * (X @ W1) -------------------------------
// 96-row wave-tiles; 64-k granules staged as 256B-contiguous-per-row (R16
// probe_c: 5.9 TB/s vs 3.5 for 64B granules). W slice (192k x 16) restaged in
// LDS per split inside the kernel -> no k-split grid, no hpart/reduce. LDS
// issue budget: W 1.5M + x 2.25M + wr 0.56M ~ 56us < 97us HBM floor.

// fast path: 8 rows (4*(BI)..4*(BI+7)+Lr), internal k-tail guard
#define LX8_F(KO, BI, A0,A1,A2,A3,A4,A5,A6,A7)                           \
  { if ((KO) + 64 <= K_IN) {                                             \
      A0 = *(const f4u*)(xrow + (size_t)(4*((BI)+0))*K_IN + (KO));       \
      A1 = *(const f4u*)(xrow + (size_t)(4*((BI)+1))*K_IN + (KO));       \
      A2 = *(const f4u*)(xrow + (size_t)(4*((BI)+2))*K_IN + (KO));       \
      A3 = *(const f4u*)(xrow + (size_t)(4*((BI)+3))*K_IN + (KO));       \
      A4 = *(const f4u*)(xrow + (size_t)(4*((BI)+4))*K_IN + (KO));       \
      A5 = *(const f4u*)(xrow + (size_t)(4*((BI)+5))*K_IN + (KO));       \
      A6 = *(const f4u*)(xrow + (size_t)(4*((BI)+6))*K_IN + (KO));       \
      A7 = *(const f4u*)(xrow + (size_t)(4*((BI)+7))*K_IN + (KO));       \
    } else {                                                             \
      A0=0.f;A1=0.f;A2=0.f;A3=0.f;A4=0.f;A5=0.f;A6=0.f;A7=0.f;           \
      _Pragma("unroll")                                                  \
      for (int m_ = 0; m_ < 4; ++m_) {                                   \
        int k_ = (KO) + 4*Lq + m_;                                       \
        if (k_ < K_IN) {                                                 \
          A0[m_] = xrow[(size_t)(4*((BI)+0))*K_IN + (KO) + m_];          \
          A1[m_] = xrow[(size_t)(4*((BI)+1))*K_IN + (KO) + m_];          \
          A2[m_] = xrow[(size_t)(4*((BI)+2))*K_IN + (KO) + m_];          \
          A3[m_] = xrow[(size_t)(4*((BI)+3))*K_IN + (KO) + m_];          \
          A4[m_] = xrow[(size_t)(4*((BI)+4))*K_IN + (KO) + m_];          \
          A5[m_] = xrow[(size_t)(4*((BI)+5))*K_IN + (KO) + m_];          \
          A6[m_] = xrow[(size_t)(4*((BI)+6))*K_IN + (KO) + m_];          \
          A7[m_] = xrow[(size_t)(4*((BI)+7))*K_IN + (KO) + m_];          \
        }                                                                \
      }                                                                  \
    } }

// clamped path (last tile only): per-element row+k guards, scalar loads
#define LX1_C(KO, I, A)                                                  \
  { A = 0.f;                                                             \
    int r_ = min(base + Lr + 4*(I), N_NODES - 1);                        \
    const float* xr_ = X + (size_t)r_ * K_IN + 4 * Lq;                   \
    _Pragma("unroll")                                                    \
    for (int m_ = 0; m_ < 4; ++m_) {                                     \
      int k_ = (KO) + 4*Lq + m_;                                         \
      if (k_ < K_IN) A[m_] = xr_[(KO) + m_];                             \
    } }

#define LOADX(KO)                                                        \
  { if (safe) {                                                          \
      LX8_F(KO, 0,  p00,p01,p02,p03,p04,p05,p06,p07)                     \
      LX8_F(KO, 8,  p08,p09,p10,p11,p12,p13,p14,p15)                     \
      LX8_F(KO, 16, p16,p17,p18,p19,p20,p21,p22,p23)                     \
    } else {                                                             \
      LX1_C(KO, 0,p00)  LX1_C(KO, 1,p01)  LX1_C(KO, 2,p02)               \
      LX1_C(KO, 3,p03)  LX1_C(KO, 4,p04)  LX1_C(KO, 5,p05)               \
      LX1_C(KO, 6,p06)  LX1_C(KO, 7,p07)  LX1_C(KO, 8,p08)               \
      LX1_C(KO, 9,p09)  LX1_C(KO,10,p10)  LX1_C(KO,11,p11)               \
      LX1_C(KO,12,p12)  LX1_C(KO,13,p13)  LX1_C(KO,14,p14)               \
      LX1_C(KO,15,p15)  LX1_C(KO,16,p16)  LX1_C(KO,17,p17)               \
      LX1_C(KO,18,p18)  LX1_C(KO,19,p19)  LX1_C(KO,20,p20)               \
      LX1_C(KO,21,p21)  LX1_C(KO,22,p22)  LX1_C(KO,23,p23)               \
    } }

#define WR1(I, A) *(f4*)(xbw + (I)*4*SX3) = A;
#define WRX                                                              \
  { WR1(0,p00) WR1(1,p01) WR1(2,p02) WR1(3,p03) WR1(4,p04) WR1(5,p05)    \
    WR1(6,p06) WR1(7,p07) WR1(8,p08) WR1(9,p09) WR1(10,p10) WR1(11,p11)  \
    WR1(12,p12) WR1(13,p13) WR1(14,p14) WR1(15,p15) WR1(16,p16)          \
    WR1(17,p17) WR1(18,p18) WR1(19,p19) WR1(20,p20) WR1(21,p21)          \
    WR1(22,p22) WR1(23,p23) }

#define CFMA(GOFF)                                                       \
  { _Pragma("unroll")                                                    \
    for (int kq = 0; kq < 16; ++kq) {                                    \
      f4 x0 = *(const f4*)(xrd + 0*16*SX3 + kq*4);                       \
      f4 x1 = *(const f4*)(xrd + 1*16*SX3 + kq*4);                       \
      f4 x2 = *(const f4*)(xrd + 2*16*SX3 + kq*4);                       \
      f4 x3 = *(const f4*)(xrd + 3*16*SX3 + kq*4);                       \
      f4 x4 = *(const f4*)(xrd + 4*16*SX3 + kq*4);                       \
      f4 x5 = *(const f4*)(xrd + 5*16*SX3 + kq*4);                       \
      const float* wb = wlds + ((GOFF) + kq*4)*NH + jq*4;                \
      f4 w0 = *(const f4*)(wb);                                          \
      f4 w1 = *(const f4*)(wb + NH);                                     \
      f4 w2 = *(const f4*)(wb + 2*NH);                                   \
      f4 w3 = *(const f4*)(wb + 3*NH);                                   \
      a0 += x0[0]*w0; a0 += x0[1]*w1; a0 += x0[2]*w2; a0 += x0[3]*w3;    \
      a1 += x1[0]*w0; a1 += x1[1]*w1; a1 += x1[2]*w2; a1 += x1[3]*w3;    \
      a2 += x2[0]*w0; a2 += x2[1]*w1; a2 += x2[2]*w2; a2 += x2[3]*w3;    \
      a3 += x3[0]*w0; a3 += x3[1]*w1; a3 += x3[2]*w2; a3 += x3[3]*w3;    \
      a4 += x4[0]*w0; a4 += x4[1]*w1; a4 += x4[2]*w2; a4 += x4[3]*w3;    \
      a5 += x5[0]*w0; a5 += x5[1]*w1; a5 += x5[2]*w2; a5 += x5[3]*w3;    \
    } }

__global__ __launch_bounds__(128)
void k_gemm1(const float* __restrict__ X, const float* __restrict__ W1,
             const int* __restrict__ deg_out, float* __restrict__ h) {
    __shared__ float wlds[192 * NH];               // 12288 B
    __shared__ float sX[2][TR3 * SX3];             // 2 x 26112 B
    const int wid = threadIdx.x >> 6;
    const int t   = threadIdx.x & 63;
    const int tile = blockIdx.x * 2 + wid;         // 521*2 = 1042 exact
    const int base = tile * TR3;
    const int Lq = t & 15;                         // 16B slice of 256B span
    const int Lr = t >> 4;                         // staging row 0..3
    const int rg = t >> 2;                         // compute row-group 0..15
    const int jq = t & 3;                          // compute j-quad
    const bool safe = (base + TR3 <= N_NODES);     // false only for tile 1041

    const float* xrow = X + (size_t)(base + Lr) * K_IN + 4 * Lq;
    float* xbuf = sX[wid];
    float* xbw  = xbuf + Lr * SX3 + 4 * Lq;
    const float* xrd = xbuf + rg * SX3;
    const f4* W1v = (const f4*)W1;

    f4 a0 = 0.f, a1 = 0.f, a2 = 0.f, a3 = 0.f, a4 = 0.f, a5 = 0.f;
    f4 p00,p01,p02,p03,p04,p05,p06,p07,p08,p09,p10,p11;
    f4 p12,p13,p14,p15,p16,p17,p18,p19,p20,p21,p22,p23;

    LOADX(0)                                       // prologue: granule 0

#pragma unroll 1
    for (int s = 0; s < NSPL; ++s) {
        // restage this split's W slice (prior CFMA done; P loads in flight)
        __syncthreads();
#pragma unroll
        for (int r = 0; r < 6; ++r) {
            int idx  = r * 128 + threadIdx.x;      // f4 index 0..767
            int krow = s * 192 + (idx >> 2);
            f4 wv = 0.f;
            if (krow < K_IN) wv = W1v[krow * 4 + (idx & 3)];
            ((f4*)wlds)[idx] = wv;
        }
        __syncthreads();
        const int kb = s * 192;
        // granule 0
        WRX
        LOADX(kb + 64)
        __builtin_amdgcn_wave_barrier();
        CFMA(0)
        __builtin_amdgcn_wave_barrier();
        // granule 1
        WRX
        LOADX(kb + 128)
        __builtin_amdgcn_wave_barrier();
        CFMA(64)
        __builtin_amdgcn_wave_barrier();
        // granule 2
        WRX
        if (s + 1 < NSPL) { LOADX(kb + 192) }      // prefetch next split's g0
        __builtin_amdgcn_wave_barrier();
        CFMA(128)
        __builtin_amdgcn_wave_barrier();
    }

    // epilogue: norm_src applied here (no hpart / reduce pass)
#pragma unroll
    for (int m = 0; m < 6; ++m) {
        int row = base + rg + 16 * m;
        if (row < N_NODES) {
            f4 av = (m==0)?a0:(m==1)?a1:(m==2)?a2:(m==3)?a3:(m==4)?a4:a5;
            float ns = rsqrtf((float)max(deg_out[row], 1));
            *(f4*)(h + (size_t)row * NH + jq * 4) = av * ns;
        }
    }
}

// ---------------- K4: gather layer1 + relu + fused (.. @ W2) ----------------
__global__ __launch_bounds__(256)
void k_layer1(const float* __restrict__ h, const int* __restrict__ adj,
              const int* __restrict__ cnt, const int* __restrict__ deg_out,
              const float* __restrict__ W2, const float* __restrict__ b1,
              float* __restrict__ g) {
    const int lane = threadIdx.x & 63;
    const int wid  = threadIdx.x >> 6;
    const int d    = blockIdx.x * 4 + wid;
    if (d >= N_NODES) return;
    const int j4 = lane & 3, slot = lane >> 2;
    const int start = d * SLOT;
    const int deg   = min(cnt[d], SLOT);
    const int end   = start + deg;
    f4 agg = 0.f;
    for (int p = start + slot; p < end; p += 16) {
        int s = adj[p];
        agg += ((const f4*)h)[s * 4 + j4];
    }
#pragma unroll
    for (int off = 4; off < 64; off <<= 1) {
        agg[0] += __shfl_xor(agg[0], off);
        agg[1] += __shfl_xor(agg[1], off);
        agg[2] += __shfl_xor(agg[2], off);
        agg[3] += __shfl_xor(agg[3], off);
    }
    __shared__ float st[4][NH];
    const float nd = rsqrtf((float)max(deg, 1));
    if (slot == 0) {
        f4 bb = ((const f4*)b1)[j4];
        f4 tj;
        tj[0] = fmaxf(fmaf(agg[0], nd, bb[0]), 0.f);
        tj[1] = fmaxf(fmaf(agg[1], nd, bb[1]), 0.f);
        tj[2] = fmaxf(fmaf(agg[2], nd, bb[2]), 0.f);
        tj[3] = fmaxf(fmaf(agg[3], nd, bb[3]), 0.f);
        ((f4*)st[wid])[j4] = tj;
    }
    __builtin_amdgcn_wave_barrier();
    float r = 0.f;
    if (lane < NO) {
#pragma unroll
        for (int qq = 0; qq < NH; ++qq)
            r = fmaf(st[wid][qq], W2[qq * NO + lane], r);
    }
    if (lane < 8) {
        float ns = rsqrtf((float)max(deg_out[d], 1));
        g[(size_t)d * 8 + lane] = (lane < NO) ? ns * r : 0.f;
    }
}

// ---------------- K5: gather layer2 -> out ----------------
__global__ __launch_bounds__(256)
void k_layer2(const float* __restrict__ g, const int* __restrict__ adj,
              const int* __restrict__ cnt, const float* __restrict__ b2,
              float* __restrict__ out) {
    const int lane = threadIdx.x & 63;
    const int wid  = threadIdx.x >> 6;
    const int d    = blockIdx.x * 4 + wid;
    if (d >= N_NODES) return;
    const int o4 = lane & 1, slot = lane >> 1;
    const int start = d * SLOT;
    const int deg   = min(cnt[d], SLOT);
    const int end   = start + deg;
    f4 agg = 0.f;
    for (int p = start + slot; p < end; p += 32) {
        int s = adj[p];
        agg += ((const f4*)g)[s * 2 + o4];
    }
#pragma unroll
    for (int off = 2; off < 64; off <<= 1) {
        agg[0] += __shfl_xor(agg[0], off);
        agg[1] += __shfl_xor(agg[1], off);
        agg[2] += __shfl_xor(agg[2], off);
        agg[3] += __shfl_xor(agg[3], off);
    }
    const int sl = lane >> 2;
    float v0 = __shfl(agg[0], sl);
    float v1 = __shfl(agg[1], sl);
    float v2 = __shfl(agg[2], sl);
    float v3 = __shfl(agg[3], sl);
    int cm = lane & 3;
    float v = (cm == 0) ? v0 : (cm == 1) ? v1 : (cm == 2) ? v2 : v3;
    if (lane < NO) {
        float nd = rsqrtf((float)max(deg, 1));
        out[(size_t)d * NO + lane] = fmaf(v, nd, b2[lane]);
    }
}

extern "C" void kernel_launch(void* const* d_in, const int* in_sizes, int n_in,
                              void* d_out, int out_size, void* d_ws, size_t ws_size,
                              hipStream_t stream) {
    const float* X   = (const float*)d_in[0];
    const int*   src = (const int*)d_in[1];
    const int*   dst = (const int*)d_in[2];
    const float* W1  = (const float*)d_in[3];
    const float* b1  = (const float*)d_in[4];
    const float* W2  = (const float*)d_in[5];
    const float* b2  = (const float*)d_in[6];
    float* out = (float*)d_out;

    char* w = (char*)d_ws;
    float* h        = (float*)w;  w += (size_t)N_NODES * NH * 4;          // 6.4 MB
    float* g        = (float*)w;  w += (size_t)N_NODES * 8 * 4;           // 3.2 MB
    int*   adj      = (int*)w;    w += (size_t)N_NODES * SLOT * 4;        // 38.4 MB
    int*   deg_out_a= (int*)w;    w += (size_t)N_NODES * 4;
    int*   cnt      = (int*)w;    w += (size_t)N_NODES * 4;
    int2*  ebuf     = (int2*)w;   w += (size_t)N_EDGES * 8;               // 25.6 MB
    int*   sbuf     = (int*)w;    w += (size_t)N_EDGES * 4;               // 12.8 MB
    int*   partial_d= (int*)w;    w += (size_t)SBLK * NBKT * 4;
    int*   partial_s= (int*)w;    w += (size_t)SBLK * NBKT * 4;
    int*   pbase_d  = (int*)w;    w += (size_t)SBLK * NBKT * 4;
    int*   pbase_s  = (int*)w;    w += (size_t)SBLK * NBKT * 4;
    int*   btot_d   = (int*)w;    w += NBKT * 4;
    int*   btot_s   = (int*)w;    w += NBKT * 4;
    int*   bbase_d  = (int*)w;    w += NBKT * 4;
    int*   bbase_s  = (int*)w;    w += NBKT * 4;

    // ---- atomic-free graph build (fused: 9 kernels -> 5) ----
    k_pcount2      <<<SBLK, 256, 0, stream>>>(src, dst, partial_s, partial_d);
    k_colscan2     <<<2 * NBKT, 256, 0, stream>>>(partial_d, pbase_d, btot_d,
                                                  partial_s, pbase_s, btot_s);
    k_basescan     <<<1, 256, 0, stream>>>(btot_d, bbase_d, btot_s, bbase_s);
    k_pscatter_both<<<SBLK, 256, 0, stream>>>(src, dst, pbase_d, bbase_d, ebuf,
                                              pbase_s, bbase_s, sbuf);
    k_adj_hist     <<<NBKT, 512, 0, stream>>>(ebuf, bbase_d, btot_d, adj, cnt,
                                              sbuf, bbase_s, btot_s, deg_out_a);

    // ---- GCN pipeline (gemm1 writes h directly; no reduce) ----
    k_gemm1 <<<521, 128, 0, stream>>>(X, W1, deg_out_a, h);
    k_layer1<<<(N_NODES + 3) / 4, 256, 0, stream>>>(h, adj, cnt, deg_out_a,
                                                    W2, b1, g);
    k_layer2<<<(N_NODES + 3) / 4, 256, 0, stream>>>(g, adj, cnt, b2, out);
}